// Round 11
// baseline (176.244 us; speedup 1.0000x reference)
//
#include <hip/hip_runtime.h>
#include <math.h>

// VIN forward on MI355X — single fused kernel, 128 WGs x 512 thr (8 waves).
// Sizes: N=128, H=W=64, CH_I=2, CH_H=150, CH_Q=10, N_ACT=8, VInum=36.
//
// R20 -> R21 (single change: weight residency, now in VGPRs, FORCED):
//  R20 (SGPR pin) failed on arithmetic: 90 SGPRs > ~102-wave budget minus
//  bases -> scratch (FETCH rose). Surviving theory: K-loop VALU idles 69%
//  because each wave re-loads 90 weight floats/iter via the shared scalar
//  pipe (720 SMEM/CU/iter) + lgkmcnt(0) drains that also flush DS. Every
//  residency file failed EXCEPT VGPR-at-512thr with remat BLOCKED: R18's
//  compiler chose 128 VGPR + remat; asm "+v" pins close that escape.
//  Structure = R19's DPP/column-lane (best, 102us) at 8 waves: lane=col,
//  wave w owns rows 8w..8w+7 (8 px/thread, vprev[8]); horizontal neighbors
//  via DPP wave_shr/shl (zero halo at lanes 0/63); vertical edges via tiny
//  parity-double-buffered exT/exB[2][9][64] (slot 8 = zero halo): 2 b32
//  reads + 2 b32 writes per thread per iter. K-loop = pure VALU + 4 DS ops
//  + barrier; NO in-loop SMEM. Budget: weights 90 + Rsw2 80 + vprev 8 +
//  windows 30 + acc 40 (px-halved) + misc ~= 248 <= 256.
//  d=0..8 chain order, identical operand floats -> bit-identical output.

typedef float v2f __attribute__((ext_vector_type(2)));

static __device__ __forceinline__ v2f splat2(float s) { v2f r; r.x = s; r.y = s; return r; }
static __device__ __forceinline__ v2f pkfma(v2f w, float v, v2f a) {
#if __has_builtin(__builtin_elementwise_fma)
    return __builtin_elementwise_fma(w, splat2(v), a);
#else
    v2f r; r.x = fmaf(w.x, v, a.x); r.y = fmaf(w.y, v, a.y); return r;
#endif
}
static __device__ __forceinline__ v2f pkmax(v2f a, v2f b) {
#if __has_builtin(__builtin_elementwise_max)
    return __builtin_elementwise_max(a, b);
#else
    v2f r; r.x = fmaxf(a.x, b.x); r.y = fmaxf(a.y, b.y); return r;
#endif
}

// DPP wave-wide shift by one lane. bound-invalid lanes keep old (=0) ->
// zero halo at lanes 0/63.
#define DPP_SHR1 0x138   // lane n <- lane n-1  (left-neighbor value)
#define DPP_SHL1 0x130   // lane n <- lane n+1  (right-neighbor value)
template <int CTRL>
static __device__ __forceinline__ float dppsh(float v) {
    return __int_as_float(__builtin_amdgcn_update_dpp(
        0, __float_as_int(v), CTRL, 0xF, 0xF, false));
}

#define XROW 69
#define RROW 68                  // rs row stride; idx = (grow+1)*68 + col + 2

__global__ void
__attribute__((amdgpu_flat_work_group_size(512, 512)))
__attribute__((amdgpu_waves_per_eu(2, 2)))
vin_kernel(const float* __restrict__ x,
           const int* __restrict__ S1,
           const int* __restrict__ S2,
           const int* __restrict__ VInum,
           const float* __restrict__ w0,
           const float* __restrict__ b0,
           const float* __restrict__ w_r,
           const float* __restrict__ w_q,
           const float* __restrict__ w_sw,
           const float* __restrict__ w_sw2,
           const float* __restrict__ w_dense,
           float* __restrict__ out) {
    const int b = blockIdx.x;
    const int t = threadIdx.x;

    __shared__ float xs0[68 * XROW];     // x ch0, [y+2][x+2], 2-halo of zeros
    __shared__ float xs1[68 * XROW];     // x ch1
    __shared__ float rs[66 * RROW];      // r, pad-2 layout, zero halos
    __shared__ float wtA[1620];          // P chunk partials: 162 entries x 10
    __shared__ float Pp[450];            // P[d][e5x5][ci], zero-init
    __shared__ float Bt[90];             // bias chunk partials
    __shared__ float Bv[9];              // B[d] = w_r[d].b0
    __shared__ float W5c[459];           // 9 classes x (50 weights + bias)
    __shared__ float exT[2][9][64];      // per-wave TOP-row edge, by parity
    __shared__ float exB[2][9][64];      // per-wave BOTTOM-row edge, by parity
    __shared__ float qsel[10];

    // ---- zero LDS (halos/slot-8 must be 0; Pp must be 0) ----
    for (int i = t; i < 68 * XROW; i += 512) { xs0[i] = 0.f; xs1[i] = 0.f; }
    for (int i = t; i < 66 * RROW; i += 512) rs[i] = 0.f;
    for (int i = t; i < 2 * 9 * 64; i += 512) {
        ((float*)exT)[i] = 0.f; ((float*)exB)[i] = 0.f;
    }
    if (t < 450) Pp[t] = 0.f;
    __syncthreads();

    const int row = t >> 3;          // 0..63 (prologue mapping)
    const int cb  = (t & 7) << 3;    // 0,8,...,56

    // ---- stage x (16 contiguous floats = 4x float4 per thread) ----
    {
        const float* xb = x + (size_t)b * 64 * 64 * 2;
        const float4* xp = (const float4*)(xb + (row * 64 + cb) * 2);
        #pragma unroll
        for (int g = 0; g < 4; ++g) {
            float4 v4 = xp[g];
            int px = cb + g * 2;
            xs0[(row + 2) * XROW + px + 2] = v4.x;
            xs1[(row + 2) * XROW + px + 2] = v4.y;
            xs0[(row + 2) * XROW + px + 3] = v4.z;
            xs1[(row + 2) * XROW + px + 3] = v4.w;
        }
    }
    // ---- round A: P chunk partials (1620 items) + bias chunks (90) ----
    for (int idx = t; idx < 1620; idx += 512) {
        int entry = idx / 10, ch = idx - entry * 10;
        int d = entry / 18, rem = entry % 18;
        int uu = rem >> 1, ci = rem & 1;
        int c0 = ch * 15;
        const float* wr = w_r + d * 150;
        const float* wp = w0 + (uu * 2 + ci) * 150;
        float s = 0.f;
        for (int c = c0; c < c0 + 15; ++c) s += wr[c] * wp[c];
        wtA[idx] = s;
    }
    if (t < 90) {
        int d = t / 10, ch = t - d * 10, c0 = ch * 15;
        float s = 0.f;
        for (int c = c0; c < c0 + 15; ++c) s += w_r[d * 150 + c] * b0[c];
        Bt[t] = s;
    }
    __syncthreads();
    // ---- round B: reduce P entries (162) and B (9) ----
    if (t < 162) {
        float s = 0.f;
        #pragma unroll
        for (int i = 0; i < 10; ++i) s += wtA[t * 10 + i];
        int d = t / 18, rem = t % 18;
        int uu = rem >> 1, ci = rem & 1;
        int dy = d / 3 - 1, dx = d % 3 - 1;
        int uy = uu / 3 - 1, ux = uu % 3 - 1;
        int eidx = (dy + uy + 2) * 5 + (dx + ux + 2);
        Pp[d * 50 + eidx * 2 + ci] = s;
    } else if (t >= 256 && t < 265) {
        int d = t - 256;
        float s = 0.f;
        #pragma unroll
        for (int i = 0; i < 10; ++i) s += Bt[d * 10 + i];
        Bv[d] = s;
    }
    __syncthreads();
    // ---- round C: class subset-sums W5c[9][51] ----
    if (t < 459) {
        int cls = t / 51, j = t - cls * 51;
        int cy = cls / 3, cx = cls % 3;
        float s = 0.f;
        #pragma unroll
        for (int d = 0; d < 9; ++d) {
            int dy = d / 3 - 1, dx = d % 3 - 1;
            bool ok = (cy == 0 || (cy == 1 ? dy >= 0 : dy <= 0)) &&
                      (cx == 0 || (cx == 1 ? dx >= 0 : dx <= 0));
            if (ok) s += (j < 50) ? Pp[d * 50 + j] : Bv[d];
        }
        W5c[t] = s;
    }
    __syncthreads();

    // ---- r everywhere via class-weighted 5x5 stencil (8 px/thread) ----
    {
        int cy = (row == 0) ? 1 : (row == 63) ? 2 : 0;
        #pragma unroll
        for (int p = 0; p < 8; ++p) {
            int xx = cb + p;
            int cx = (xx == 0) ? 1 : (xx == 63) ? 2 : 0;
            const float* Wp = &W5c[(cy * 3 + cx) * 51];
            float acc = Wp[50];
            #pragma unroll
            for (int e = 0; e < 25; ++e) {
                int xi = (row + e / 5) * XROW + (xx + e % 5);
                acc = fmaf(xs0[xi], Wp[e * 2], acc);
                acc = fmaf(xs1[xi], Wp[e * 2 + 1], acc);
            }
            rs[(row + 1) * RROW + xx + 2] = acc;
        }
    }
    __syncthreads();

    // ============ column-per-lane mapping from here on ============
    const int c  = t & 63;           // column 0..63 (lane)
    const int w  = t >> 6;           // wave 0..7, owns rows 8w..8w+7
    const int r0 = w << 3;
    const int upSlot = (w == 0) ? 8 : w - 1;   // exB[.][upSlot] = row r0-1
    const int dnSlot = (w == 7) ? 8 : w + 1;   // exT[.][dnSlot] = row r0+8
    const int K = VInum[0];

    // ---- Rsw precompute + first step (w_q): r window via DPP ----
    v2f Rsw2[8][5];
    float vprev[8];
    {
        float RC[10], RL[10], RR[10];
        #pragma unroll
        for (int j = 0; j < 10; ++j) RC[j] = rs[(r0 + j) * RROW + c + 2];
        #pragma unroll
        for (int j = 0; j < 10; ++j) {
            RL[j] = dppsh<DPP_SHR1>(RC[j]); RR[j] = dppsh<DPP_SHL1>(RC[j]);
        }
        float vmax[8];
        #pragma unroll
        for (int a = 0; a < 10; ++a) {
            #pragma unroll
            for (int i = 0; i < 8; ++i) {
                float accR = 0.f, accQ = 0.f;
                #pragma unroll
                for (int d = 0; d < 9; ++d) {
                    const int dy = d / 3, dx = d % 3;
                    const float rv = (dx == 0 ? RL : dx == 1 ? RC : RR)[i + dy];
                    accR = fmaf(w_sw[d * 20 + a], rv, accR);
                    accQ = fmaf(w_q[d * 20 + a],  rv, accQ);
                }
                if (a & 1) Rsw2[i][a >> 1].y = accR; else Rsw2[i][a >> 1].x = accR;
                vmax[i] = (a == 0) ? accQ : fmaxf(vmax[i], accQ);
            }
        }
        exT[1][w][c] = vmax[0];          // v^1 edges, parity 1
        exB[1][w][c] = vmax[7];
        #pragma unroll
        for (int i = 0; i < 8; ++i) vprev[i] = vmax[i];
    }

    // ---- load the 45 v-part weight pairs ONCE and PIN them in VGPRs ----
    // asm "+v" blocks rematerialization (the R18/R19 escape hatch): the
    // value must stay register-resident until its last K-loop use.
    v2f wv[45];
    #pragma unroll
    for (int i = 0; i < 45; ++i) {
        const int d = i / 5, ap = i - d * 5;
        v2f v; v.x = w_sw[d * 20 + 10 + 2 * ap]; v.y = w_sw[d * 20 + 10 + 2 * ap + 1];
        asm volatile("" : "+v"(v));
        wv[i] = v;
    }
    __syncthreads();

    // ---- K-1 shared-weight VI steps: pure VALU + 4 DS ops + barrier ----
    for (int k = 2; k <= K; ++k) {
        const int pr = (k - 1) & 1, pw = k & 1;
        float VC[10], VL[10], VR[10];
        VC[0] = exB[pr][upSlot][c];      // row r0-1 (neighbor wave / halo 0)
        VC[9] = exT[pr][dnSlot][c];      // row r0+8
        #pragma unroll
        for (int i = 0; i < 8; ++i) VC[i + 1] = vprev[i];
        #pragma unroll
        for (int j = 0; j < 10; ++j) {
            VL[j] = dppsh<DPP_SHR1>(VC[j]); VR[j] = dppsh<DPP_SHL1>(VC[j]);
        }

        float vnew[8];
        // ---- half A: px 0..3 (windows VC[0..5]) ----
        {
            v2f acc[4][5];
            #pragma unroll
            for (int ap = 0; ap < 5; ++ap) {
                #pragma unroll
                for (int d = 0; d < 9; ++d) {
                    const int dy = d / 3, dx = d % 3;
                    const float* S = (dx == 0) ? VL : (dx == 1) ? VC : VR;
                    v2f w2 = wv[d * 5 + ap];
                    #pragma unroll
                    for (int i = 0; i < 4; ++i)
                        acc[i][ap] = (d == 0) ? pkfma(w2, S[i + dy], Rsw2[i][ap])
                                              : pkfma(w2, S[i + dy], acc[i][ap]);
                }
            }
            #pragma unroll
            for (int i = 0; i < 4; ++i) {
                v2f m2 = acc[i][0];
                #pragma unroll
                for (int ap = 1; ap < 5; ++ap) m2 = pkmax(m2, acc[i][ap]);
                vnew[i] = fmaxf(m2.x, m2.y);
            }
        }
        // ---- half B: px 4..7 (windows VC[4..9]) ----
        {
            v2f acc[4][5];
            #pragma unroll
            for (int ap = 0; ap < 5; ++ap) {
                #pragma unroll
                for (int d = 0; d < 9; ++d) {
                    const int dy = d / 3, dx = d % 3;
                    const float* S = (dx == 0) ? VL : (dx == 1) ? VC : VR;
                    v2f w2 = wv[d * 5 + ap];
                    #pragma unroll
                    for (int i = 0; i < 4; ++i)
                        acc[i][ap] = (d == 0) ? pkfma(w2, S[i + 4 + dy], Rsw2[i + 4][ap])
                                              : pkfma(w2, S[i + 4 + dy], acc[i][ap]);
                }
            }
            #pragma unroll
            for (int i = 0; i < 4; ++i) {
                v2f m2 = acc[i][0];
                #pragma unroll
                for (int ap = 1; ap < 5; ++ap) m2 = pkmax(m2, acc[i][ap]);
                vnew[i + 4] = fmaxf(m2.x, m2.y);
            }
        }
        exT[pw][w][c] = vnew[0];         // publish v^k edges
        exB[pw][w][c] = vnew[7];
        #pragma unroll
        for (int i = 0; i < 8; ++i) vprev[i] = vnew[i];
        __syncthreads();
    }

    // ---- final step with w_sw2: q -> global, gather (S1,S2) ----
    const int s1 = S1[b], s2 = S2[b];
    {
        const int pK = K & 1;
        float RC[10], RL[10], RR[10], VC[10], VL[10], VR[10];
        #pragma unroll
        for (int j = 0; j < 10; ++j) RC[j] = rs[(r0 + j) * RROW + c + 2];
        VC[0] = exB[pK][upSlot][c];
        VC[9] = exT[pK][dnSlot][c];
        #pragma unroll
        for (int i = 0; i < 8; ++i) VC[i + 1] = vprev[i];
        #pragma unroll
        for (int j = 0; j < 10; ++j) {
            RL[j] = dppsh<DPP_SHR1>(RC[j]); RR[j] = dppsh<DPP_SHL1>(RC[j]);
            VL[j] = dppsh<DPP_SHR1>(VC[j]); VR[j] = dppsh<DPP_SHL1>(VC[j]);
        }

        float qv[8][10];
        #pragma unroll
        for (int a = 0; a < 10; ++a) {
            #pragma unroll
            for (int i = 0; i < 8; ++i) {
                float acc = 0.f;
                #pragma unroll
                for (int d = 0; d < 9; ++d) {
                    const int dy = d / 3, dx = d % 3;
                    acc = fmaf(w_sw2[d * 20 + a],
                               (dx == 0 ? RL : dx == 1 ? RC : RR)[i + dy], acc);
                    acc = fmaf(w_sw2[d * 20 + 10 + a],
                               (dx == 0 ? VL : dx == 1 ? VC : VR)[i + dy], acc);
                }
                qv[i][a] = acc;
            }
        }
        // store q: 10 floats per px, 8B-aligned -> 5x float2 per row
        #pragma unroll
        for (int i = 0; i < 8; ++i) {
            float2* qp = (float2*)(out + 2048 +
                          ((size_t)((b * 64 + r0 + i) * 64 + c)) * 10);
            #pragma unroll
            for (int g = 0; g < 5; ++g)
                qp[g] = make_float2(qv[i][2 * g], qv[i][2 * g + 1]);
        }
        if (c == s2) {
            #pragma unroll
            for (int i = 0; i < 8; ++i)
                if (s1 == r0 + i) {
                    #pragma unroll
                    for (int a = 0; a < 10; ++a) qsel[a] = qv[i][a];
                }
        }
    }
    __syncthreads();

    // ---- dense + softmax (thread 0), q_out (threads 0..9) ----
    if (t == 0) {
        float logits[8];
        float m = -1e30f;
        #pragma unroll
        for (int j = 0; j < 8; ++j) {
            float s = 0.f;
            #pragma unroll
            for (int a = 0; a < 10; ++a) s += qsel[a] * w_dense[a * 8 + j];
            logits[j] = s;
            m = fmaxf(m, s);
        }
        float sum = 0.f;
        float e[8];
        #pragma unroll
        for (int j = 0; j < 8; ++j) { e[j] = expf(logits[j] - m); sum += e[j]; }
        float inv = 1.f / sum;
        #pragma unroll
        for (int j = 0; j < 8; ++j) {
            out[b * 8 + j] = logits[j];
            out[1024 + b * 8 + j] = e[j] * inv;
        }
    }
    if (t < 10) out[5244928 + b * 10 + t] = qsel[t];
}

extern "C" void kernel_launch(void* const* d_in, const int* in_sizes, int n_in,
                              void* d_out, int out_size, void* d_ws, size_t ws_size,
                              hipStream_t stream) {
    const float* x      = (const float*)d_in[0];
    const int*   S1     = (const int*)d_in[1];
    const int*   S2     = (const int*)d_in[2];
    const int*   VInum  = (const int*)d_in[3];
    const float* w0     = (const float*)d_in[4];
    const float* b0     = (const float*)d_in[5];
    const float* w_r    = (const float*)d_in[6];
    const float* w_q    = (const float*)d_in[7];
    const float* w_sw   = (const float*)d_in[8];
    const float* w_sw2  = (const float*)d_in[9];
    const float* w_dense= (const float*)d_in[10];
    float* out = (float*)d_out;

    vin_kernel<<<128, 512, 0, stream>>>(x, S1, S2, VInum, w0, b0, w_r, w_q,
                                        w_sw, w_sw2, w_dense, out);
}